// Round 1
// baseline (308.328 us; speedup 1.0000x reference)
//
#include <hip/hip_runtime.h>
#include <type_traits>

// Problem: B=2, S=2048, D=1024, H=16, HD=64. fp32 in/out.
// Pipeline exploits head-summed K/V: k_sum = x @ (sum_h Wk_h)^T + sum_h bk_h.
//  1. prep_convert: x, Wq, Wout -> f16 (RNE via v_cvt)
//  2. prep_wred:    head-reduced Wk/Wv (128x1024) + biases
//  3. gemm_bt<f16>: Q = x @ Wq^T + bq            (4096x1024x1024)
//  4. gemm_bt<f16>: kv = x @ Wred^T + bred       (4096x128x1024)
//  5. flash_attn:   online-softmax, K/V shared across heads (HD=64)
//  6. gemm_bt<f32>: out = ao @ Wout^T + bout     (4096x1024x1024)

#define S_LEN 2048
#define DIM 1024
#define NH 16
#define HD 64

using floatx4 = __attribute__((ext_vector_type(4))) float;
using halfx8  = __attribute__((ext_vector_type(8))) _Float16;
using halfx4  = __attribute__((ext_vector_type(4))) _Float16;

__device__ __forceinline__ floatx4 mfma16(halfx8 a, halfx8 b, floatx4 c) {
  return __builtin_amdgcn_mfma_f32_16x16x32_f16(a, b, c, 0, 0, 0);
}

// ---------------- prep: fp32 -> f16 conversions ----------------
__global__ __launch_bounds__(256) void prep_convert(
    const float* __restrict__ x, const float* __restrict__ wqkv,
    const float* __restrict__ wout,
    _Float16* __restrict__ xb, _Float16* __restrict__ wqb,
    _Float16* __restrict__ woutb) {
  size_t gid = (size_t)blockIdx.x * 256 + threadIdx.x;
  size_t i4 = gid * 4;
  if (i4 >= 6291456) return;
  const float* src;
  _Float16* dst;
  size_t off;
  if (i4 < 4194304) { src = x; dst = xb; off = i4; }
  else if (i4 < 5242880) { src = wqkv; dst = wqb; off = i4 - 4194304; }
  else { src = wout; dst = woutb; off = i4 - 5242880; }
  float4 v = *(const float4*)(src + off);
  halfx4 o;
  o[0] = (_Float16)v.x; o[1] = (_Float16)v.y;
  o[2] = (_Float16)v.z; o[3] = (_Float16)v.w;
  *(halfx4*)(dst + off) = o;
}

// ---------------- prep: head-reduced K/V weights ----------------
__global__ __launch_bounds__(256) void prep_wred(
    const float* __restrict__ wqkv, const float* __restrict__ bqkv,
    _Float16* __restrict__ wredb, float* __restrict__ bred) {
  int gid = blockIdx.x * 256 + threadIdx.x;  // 131072 threads
  int c = gid >> 10, j = gid & 1023;
  int row0 = (c < 64) ? (1024 + c) : (2048 + c - 64);
  float s = 0.f;
#pragma unroll
  for (int h = 0; h < 16; ++h) s += wqkv[(size_t)(row0 + h * 64) * 1024 + j];
  wredb[gid] = (_Float16)s;
  if (gid < 128) {
    int b0 = (gid < 64) ? (1024 + gid) : (2048 + gid - 64);
    float sb = 0.f;
#pragma unroll
    for (int h = 0; h < 16; ++h) sb += bqkv[b0 + h * 64];
    bred[gid] = sb;
  }
}

// ---------------- generic GEMM: C = A @ W^T + bias ----------------
// A: M x K row-major f16. W: N x K row-major f16. C: M x ldc (OT).
// Block: 64x64 C-tile, 256 threads (4 waves, wave w -> rows w*16..+16).
template <typename OT>
__global__ __launch_bounds__(256) void gemm_bt(
    const _Float16* __restrict__ A, const _Float16* __restrict__ W,
    const float* __restrict__ bias, OT* __restrict__ C, int K, int ldc) {
  __shared__ _Float16 As[64][72];  // +8 pad (16B) to break b128 bank aliasing
  __shared__ _Float16 Ws[64][72];
  int tid = threadIdx.x;
  int lane = tid & 63, w = tid >> 6, ln = lane & 15, q4 = lane >> 4;
  int m0 = blockIdx.y * 64, n0 = blockIdx.x * 64;
  int sr = tid >> 2, sc = (tid & 3) * 16;
  const _Float16* ap = A + (size_t)(m0 + sr) * K + sc;
  const _Float16* wp = W + (size_t)(n0 + sr) * K + sc;
  floatx4 acc[4] = {};
  for (int kt = 0; kt < K; kt += 64) {
    __syncthreads();
    *(halfx8*)&As[sr][sc]     = *(const halfx8*)(ap + kt);
    *(halfx8*)&As[sr][sc + 8] = *(const halfx8*)(ap + kt + 8);
    *(halfx8*)&Ws[sr][sc]     = *(const halfx8*)(wp + kt);
    *(halfx8*)&Ws[sr][sc + 8] = *(const halfx8*)(wp + kt + 8);
    __syncthreads();
#pragma unroll
    for (int ks = 0; ks < 2; ++ks) {
      halfx8 af = *(const halfx8*)&As[w * 16 + ln][ks * 32 + q4 * 8];
#pragma unroll
      for (int n = 0; n < 4; ++n) {
        halfx8 bf = *(const halfx8*)&Ws[n * 16 + ln][ks * 32 + q4 * 8];
        acc[n] = mfma16(af, bf, acc[n]);
      }
    }
  }
#pragma unroll
  for (int n = 0; n < 4; ++n) {
    int col = n0 + n * 16 + ln;
    float bv = bias[col];
#pragma unroll
    for (int i = 0; i < 4; ++i) {
      int row = m0 + w * 16 + q4 * 4 + i;
      float v = acc[n][i] + bv;
      if constexpr (std::is_same<OT, float>::value)
        C[(size_t)row * ldc + col] = v;
      else
        C[(size_t)row * ldc + col] = (_Float16)v;
    }
  }
}

// ---------------- flash attention, K/V shared across heads ----------------
// Grid (S/64, H, B); block 256 (4 waves). Wave w: q-rows s0+w*16..+16.
// kvb: (B*S) x 128 f16, cols 0..63 = k_sum, 64..127 = v_sum.
__global__ __launch_bounds__(256) void flash_attn(
    const _Float16* __restrict__ Qb, const _Float16* __restrict__ kvb,
    _Float16* __restrict__ aob) {
  __shared__ _Float16 Ks[64][72];      // K tile [t][d]
  __shared__ _Float16 Vt[64][72];      // V tile transposed [d][t]
  __shared__ _Float16 Ps[4][16][72];   // per-wave P roundtrip (C->A layout)
  int tid = threadIdx.x;
  int lane = tid & 63, w = tid >> 6, ln = lane & 15, q4 = lane >> 4;
  int s0 = blockIdx.x * 64;
  int h = blockIdx.y;
  int b = blockIdx.z;
  size_t bS = (size_t)b * S_LEN;

  halfx8 aq0, aq1;  // Q fragments, resident for whole kernel
  {
    const _Float16* qp =
        Qb + (bS + s0 + w * 16 + ln) * DIM + h * HD + q4 * 8;
    aq0 = *(const halfx8*)(qp);
    aq1 = *(const halfx8*)(qp + 32);
  }
  const _Float16* kvp = kvb + bS * 128;
  int st = tid >> 2, scol = (tid & 3) * 16;

  float m_run[4], l_run[4];
  floatx4 oacc[4] = {};
#pragma unroll
  for (int i = 0; i < 4; ++i) { m_run[i] = -1e30f; l_run[i] = 0.f; }
  const float sc_log2 = 0.18033688011112042f;  // (1/sqrt(64)) * log2(e)

  for (int t0 = 0; t0 <= s0; t0 += 64) {
    __syncthreads();  // prior iteration's K/V reads done before overwrite
    {
      const _Float16* kp = kvp + (size_t)(t0 + st) * 128 + scol;
      *(halfx8*)&Ks[st][scol]     = *(const halfx8*)(kp);
      *(halfx8*)&Ks[st][scol + 8] = *(const halfx8*)(kp + 8);
      halfx8 v0 = *(const halfx8*)(kp + 64);
      halfx8 v1 = *(const halfx8*)(kp + 72);
#pragma unroll
      for (int i = 0; i < 8; ++i) {
        Vt[scol + i][st] = v0[i];
        Vt[scol + 8 + i][st] = v1[i];
      }
    }
    __syncthreads();

    // S = Q K^T (16x64 per wave)
    floatx4 sf[4];
#pragma unroll
    for (int n = 0; n < 4; ++n) {
      halfx8 b0 = *(const halfx8*)&Ks[n * 16 + ln][q4 * 8];
      halfx8 b1 = *(const halfx8*)&Ks[n * 16 + ln][32 + q4 * 8];
      floatx4 z = {};
      z = mfma16(aq0, b0, z);
      sf[n] = mfma16(aq1, b1, z);
    }
    bool diag = (t0 == s0);
#pragma unroll
    for (int n = 0; n < 4; ++n)
#pragma unroll
      for (int i = 0; i < 4; ++i) {
        float v = sf[n][i] * sc_log2;
        if (diag) {
          int t = t0 + n * 16 + ln;
          int s = s0 + w * 16 + q4 * 4 + i;
          if (t > s) v = -1e30f;
        }
        sf[n][i] = v;
      }
    // row max across 64 cols (4 frags + xor-shuffle over 16-lane group)
    float tm[4];
#pragma unroll
    for (int i = 0; i < 4; ++i)
      tm[i] = fmaxf(fmaxf(sf[0][i], sf[1][i]), fmaxf(sf[2][i], sf[3][i]));
#pragma unroll
    for (int off = 1; off < 16; off <<= 1)
#pragma unroll
      for (int i = 0; i < 4; ++i) tm[i] = fmaxf(tm[i], __shfl_xor(tm[i], off));
    float alpha[4];
#pragma unroll
    for (int i = 0; i < 4; ++i) {
      float mn = fmaxf(m_run[i], tm[i]);
      alpha[i] = exp2f(m_run[i] - mn);
      m_run[i] = mn;
    }
    // P = exp2(s - m), row sums, write P to per-wave LDS (A-layout source)
    float rs[4] = {0.f, 0.f, 0.f, 0.f};
#pragma unroll
    for (int n = 0; n < 4; ++n)
#pragma unroll
      for (int i = 0; i < 4; ++i) {
        float p = exp2f(sf[n][i] - m_run[i]);
        rs[i] += p;
        Ps[w][q4 * 4 + i][n * 16 + ln] = (_Float16)p;
      }
#pragma unroll
    for (int off = 1; off < 16; off <<= 1)
#pragma unroll
      for (int i = 0; i < 4; ++i) rs[i] += __shfl_xor(rs[i], off);
#pragma unroll
    for (int i = 0; i < 4; ++i) l_run[i] = l_run[i] * alpha[i] + rs[i];
#pragma unroll
    for (int n = 0; n < 4; ++n)
#pragma unroll
      for (int i = 0; i < 4; ++i) oacc[n][i] *= alpha[i];
    // O += P V  (P read back in A-layout; same-wave DS ops are in-order)
    halfx8 ap0 = *(const halfx8*)&Ps[w][ln][q4 * 8];
    halfx8 ap1 = *(const halfx8*)&Ps[w][ln][32 + q4 * 8];
#pragma unroll
    for (int n = 0; n < 4; ++n) {
      halfx8 bv0 = *(const halfx8*)&Vt[n * 16 + ln][q4 * 8];
      halfx8 bv1 = *(const halfx8*)&Vt[n * 16 + ln][32 + q4 * 8];
      oacc[n] = mfma16(ap0, bv0, oacc[n]);
      oacc[n] = mfma16(ap1, bv1, oacc[n]);
    }
  }
#pragma unroll
  for (int n = 0; n < 4; ++n)
#pragma unroll
    for (int i = 0; i < 4; ++i) {
      float o = oacc[n][i] / l_run[i];
      aob[(bS + s0 + w * 16 + q4 * 4 + i) * DIM + h * HD + n * 16 + ln] =
          (_Float16)o;
    }
}

extern "C" void kernel_launch(void* const* d_in, const int* in_sizes, int n_in,
                              void* d_out, int out_size, void* d_ws,
                              size_t ws_size, hipStream_t stream) {
  const float* x    = (const float*)d_in[0];
  const float* wqkv = (const float*)d_in[1];
  const float* bqkv = (const float*)d_in[2];
  const float* wout = (const float*)d_in[3];
  const float* bout = (const float*)d_in[4];
  float* out = (float*)d_out;
  char* ws = (char*)d_ws;
  // workspace layout (~29.3 MB)
  _Float16* xb    = (_Float16*)(ws);                         // 8 MB
  _Float16* qb    = (_Float16*)(ws + (8u << 20));            // 8 MB
  _Float16* aob   = (_Float16*)(ws + (16u << 20));           // 8 MB
  _Float16* kvb   = (_Float16*)(ws + (24u << 20));           // 1 MB
  _Float16* wqb   = (_Float16*)(ws + (25u << 20));           // 2 MB
  _Float16* woutb = (_Float16*)(ws + (27u << 20));           // 2 MB
  _Float16* wredb = (_Float16*)(ws + (29u << 20));           // 256 KB
  float*    bred  = (float*)(ws + (29u << 20) + (256u << 10));

  hipLaunchKernelGGL(prep_convert, dim3(6144), dim3(256), 0, stream,
                     x, wqkv, wout, xb, wqb, woutb);
  hipLaunchKernelGGL(prep_wred, dim3(512), dim3(256), 0, stream,
                     wqkv, bqkv, wredb, bred);
  hipLaunchKernelGGL((gemm_bt<_Float16>), dim3(16, 64), dim3(256), 0, stream,
                     xb, wqb, bqkv, qb, 1024, 1024);
  hipLaunchKernelGGL((gemm_bt<_Float16>), dim3(2, 64), dim3(256), 0, stream,
                     xb, wredb, bred, kvb, 1024, 128);
  hipLaunchKernelGGL(flash_attn, dim3(32, 16, 2), dim3(256), 0, stream,
                     qb, kvb, aob);
  hipLaunchKernelGGL((gemm_bt<float>), dim3(16, 64), dim3(256), 0, stream,
                     aob, woutb, bout, out, 1024, 1024);
}

// Round 2
// 263.542 us; speedup vs baseline: 1.1699x; 1.1699x over previous
//
#include <hip/hip_runtime.h>

// Problem: B=2, S=2048, D=1024, H=16, HD=64. fp32 in/out.
// Pipeline exploits head-summed K/V: k_sum = x @ (sum_h Wk_h)^T + sum_h bk_h.
//  1. prep_convert: x, Wq, Wout -> f16
//  2. prep_wred:    head-reduced Wk/Wv (128x1024) + biases
//  3. gemm_bt<0>:   Q = x @ Wq^T + bq            (4096x1024x1024) -> f16
//  4. gemm_bt<2>:   kv = x @ Wred^T + bred       (4096x128x1024) -> kb + vtb(V^T)
//  5. flash_attn2:  online-softmax; M = (s,h) flattened (128 rows/block = 8 s x 16 h)
//  6. gemm_bt<1>:   out = ao @ Wout^T + bout     (4096x1024x1024) -> f32

#define S_LEN 2048
#define DIM 1024

using floatx4 = __attribute__((ext_vector_type(4))) float;
using halfx8  = __attribute__((ext_vector_type(8))) _Float16;
using halfx4  = __attribute__((ext_vector_type(4))) _Float16;

__device__ __forceinline__ floatx4 mfma16(halfx8 a, halfx8 b, floatx4 c) {
  return __builtin_amdgcn_mfma_f32_16x16x32_f16(a, b, c, 0, 0, 0);
}

// ---------------- prep: fp32 -> f16 conversions ----------------
__global__ __launch_bounds__(256) void prep_convert(
    const float* __restrict__ x, const float* __restrict__ wqkv,
    const float* __restrict__ wout,
    _Float16* __restrict__ xb, _Float16* __restrict__ wqb,
    _Float16* __restrict__ woutb) {
  size_t gid = (size_t)blockIdx.x * 256 + threadIdx.x;
  size_t i4 = gid * 4;
  if (i4 >= 6291456) return;
  const float* src;
  _Float16* dst;
  size_t off;
  if (i4 < 4194304) { src = x; dst = xb; off = i4; }
  else if (i4 < 5242880) { src = wqkv; dst = wqb; off = i4 - 4194304; }
  else { src = wout; dst = woutb; off = i4 - 5242880; }
  float4 v = *(const float4*)(src + off);
  halfx4 o;
  o[0] = (_Float16)v.x; o[1] = (_Float16)v.y;
  o[2] = (_Float16)v.z; o[3] = (_Float16)v.w;
  *(halfx4*)(dst + off) = o;
}

// ---------------- prep: head-reduced K/V weights ----------------
__global__ __launch_bounds__(256) void prep_wred(
    const float* __restrict__ wqkv, const float* __restrict__ bqkv,
    _Float16* __restrict__ wredb, float* __restrict__ bred) {
  int gid = blockIdx.x * 256 + threadIdx.x;  // 131072 threads
  int c = gid >> 10, j = gid & 1023;
  int row0 = (c < 64) ? (1024 + c) : (2048 + c - 64);
  float s = 0.f;
#pragma unroll
  for (int h = 0; h < 16; ++h) s += wqkv[(size_t)(row0 + h * 64) * 1024 + j];
  wredb[gid] = (_Float16)s;
  if (gid < 128) {
    int b0 = (gid < 64) ? (1024 + gid) : (2048 + gid - 64);
    float sb = 0.f;
#pragma unroll
    for (int h = 0; h < 16; ++h) sb += bqkv[b0 + h * 64];
    bred[gid] = sb;
  }
}

// ---------------- generic GEMM: C = A @ W^T + bias ----------------
// MODE 0: f16 out (ldc). MODE 1: f32 out (ldc). MODE 2: KV special —
//   cols 0..63 -> kb[row*64+col] f16; cols 64..127 -> vtb[(b*64+d)*S + s] f16.
template <int MODE>
__global__ __launch_bounds__(256) void gemm_bt(
    const _Float16* __restrict__ A, const _Float16* __restrict__ W,
    const float* __restrict__ bias, void* __restrict__ Cv,
    void* __restrict__ C2v, int K, int ldc) {
  __shared__ _Float16 As[64][72];
  __shared__ _Float16 Ws[64][72];
  int tid = threadIdx.x;
  int lane = tid & 63, w = tid >> 6, ln = lane & 15, q4 = lane >> 4;
  int m0 = blockIdx.y * 64, n0 = blockIdx.x * 64;
  int sr = tid >> 2, sc = (tid & 3) * 16;
  const _Float16* ap = A + (size_t)(m0 + sr) * K + sc;
  const _Float16* wp = W + (size_t)(n0 + sr) * K + sc;
  floatx4 acc[4] = {};
  for (int kt = 0; kt < K; kt += 64) {
    __syncthreads();
    *(halfx8*)&As[sr][sc]     = *(const halfx8*)(ap + kt);
    *(halfx8*)&As[sr][sc + 8] = *(const halfx8*)(ap + kt + 8);
    *(halfx8*)&Ws[sr][sc]     = *(const halfx8*)(wp + kt);
    *(halfx8*)&Ws[sr][sc + 8] = *(const halfx8*)(wp + kt + 8);
    __syncthreads();
#pragma unroll
    for (int ks = 0; ks < 2; ++ks) {
      halfx8 af = *(const halfx8*)&As[w * 16 + ln][ks * 32 + q4 * 8];
#pragma unroll
      for (int n = 0; n < 4; ++n) {
        halfx8 bf = *(const halfx8*)&Ws[n * 16 + ln][ks * 32 + q4 * 8];
        acc[n] = mfma16(af, bf, acc[n]);
      }
    }
  }
#pragma unroll
  for (int n = 0; n < 4; ++n) {
    int col = n0 + n * 16 + ln;
    float bv = bias[col];
#pragma unroll
    for (int i = 0; i < 4; ++i) {
      int row = m0 + w * 16 + q4 * 4 + i;
      float v = acc[n][i] + bv;
      if constexpr (MODE == 0) {
        ((_Float16*)Cv)[(size_t)row * ldc + col] = (_Float16)v;
      } else if constexpr (MODE == 1) {
        ((float*)Cv)[(size_t)row * ldc + col] = v;
      } else {
        if (col < 64) {
          ((_Float16*)Cv)[(size_t)row * 64 + col] = (_Float16)v;
        } else {
          int bb = row >> 11, s = row & 2047;
          ((_Float16*)C2v)[(size_t)((bb << 6) + (col - 64)) * S_LEN + s] =
              (_Float16)v;
        }
      }
    }
  }
}

// ---------------- flash attention v2: M = (s,h) flattened ----------------
// Block tile: 128 M-rows = 8 s-values x 16 heads; 4 waves, wave w -> 32 rows
// (s = s0 + w*2 + mf for m-frag mf; h = row-in-frag). K/V staged once per
// 128 rows. kb: (B*S, 64) f16; vtb: (B, 64, S) f16 (V pre-transposed).
// Grid: 512 blocks, longest chunk first (LPT balance over causal range).
__global__ __launch_bounds__(256) void flash_attn2(
    const _Float16* __restrict__ Qb, const _Float16* __restrict__ kb,
    const _Float16* __restrict__ vtb, _Float16* __restrict__ aob) {
  __shared__ _Float16 Ks[64][72];      // K tile [t][d], pitch 144 B
  __shared__ _Float16 Vt[64][72];      // V^T tile [d][t]
  __shared__ _Float16 Ps[4][32][80];   // per-wave P roundtrip, pitch 160 B
  int tid = threadIdx.x;
  int lane = tid & 63, w = tid >> 6, ln = lane & 15, q4 = lane >> 4;
  int rank = blockIdx.x;
  int c = 255 - (rank >> 1);   // longest-first
  int b = rank & 1;
  int s0 = c * 8;
  size_t bS = (size_t)b * S_LEN;
  const _Float16* kbase = kb + bS * 64;
  const _Float16* vbase = vtb + (size_t)b * 64 * S_LEN;

  int sA = s0 + w * 2;  // s for m-frag 0; +1 for m-frag 1
  halfx8 aq[2][2];      // Q fragments: [mf][kh], A[m=ln -> h][k=d]
#pragma unroll
  for (int mf = 0; mf < 2; ++mf)
#pragma unroll
    for (int kh = 0; kh < 2; ++kh)
      aq[mf][kh] = *(const halfx8*)(Qb + (bS + sA + mf) * DIM + ln * 64 +
                                    kh * 32 + q4 * 8);

  float m_run[2][4], l_run[2][4];
  floatx4 oacc[2][4] = {};
#pragma unroll
  for (int mf = 0; mf < 2; ++mf)
#pragma unroll
    for (int i = 0; i < 4; ++i) { m_run[mf][i] = -1e30f; l_run[mf][i] = 0.f; }
  const float sc_log2 = 0.18033688011112042f;  // (1/sqrt(64)) * log2(e)
  int st = tid >> 2, sc = (tid & 3) * 16;
  int nt = s0 / 64 + 1;

  for (int it = 0; it < nt; ++it) {
    int t0 = it * 64;
    __syncthreads();
    *(halfx8*)&Ks[st][sc]     = *(const halfx8*)(kbase + (size_t)(t0 + st) * 64 + sc);
    *(halfx8*)&Ks[st][sc + 8] = *(const halfx8*)(kbase + (size_t)(t0 + st) * 64 + sc + 8);
    *(halfx8*)&Vt[st][sc]     = *(const halfx8*)(vbase + (size_t)st * S_LEN + t0 + sc);
    *(halfx8*)&Vt[st][sc + 8] = *(const halfx8*)(vbase + (size_t)st * S_LEN + t0 + sc + 8);
    __syncthreads();

    // S = Q K^T : per wave 2 m-frags x 4 n-frags
    floatx4 sf[2][4];
#pragma unroll
    for (int n = 0; n < 4; ++n) {
      halfx8 bk0 = *(const halfx8*)&Ks[n * 16 + ln][q4 * 8];
      halfx8 bk1 = *(const halfx8*)&Ks[n * 16 + ln][32 + q4 * 8];
#pragma unroll
      for (int mf = 0; mf < 2; ++mf) {
        floatx4 z = {};
        z = mfma16(aq[mf][0], bk0, z);
        sf[mf][n] = mfma16(aq[mf][1], bk1, z);
      }
    }
    // scale + causal mask (s uniform per m-frag)
#pragma unroll
    for (int mf = 0; mf < 2; ++mf) {
      int s_abs = sA + mf;
      bool tail = (t0 + 63 > s_abs);
#pragma unroll
      for (int n = 0; n < 4; ++n) {
        bool msk = tail && (t0 + n * 16 + ln > s_abs);
#pragma unroll
        for (int i = 0; i < 4; ++i)
          sf[mf][n][i] = msk ? -1e30f : sf[mf][n][i] * sc_log2;
      }
    }
    // row max (across 16 ln lanes)
    float tm[2][4];
#pragma unroll
    for (int mf = 0; mf < 2; ++mf)
#pragma unroll
      for (int i = 0; i < 4; ++i)
        tm[mf][i] = fmaxf(fmaxf(sf[mf][0][i], sf[mf][1][i]),
                          fmaxf(sf[mf][2][i], sf[mf][3][i]));
#pragma unroll
    for (int off = 1; off < 16; off <<= 1)
#pragma unroll
      for (int mf = 0; mf < 2; ++mf)
#pragma unroll
        for (int i = 0; i < 4; ++i)
          tm[mf][i] = fmaxf(tm[mf][i], __shfl_xor(tm[mf][i], off));
    float alpha[2][4];
#pragma unroll
    for (int mf = 0; mf < 2; ++mf)
#pragma unroll
      for (int i = 0; i < 4; ++i) {
        float mn = fmaxf(m_run[mf][i], tm[mf][i]);
        alpha[mf][i] = exp2f(m_run[mf][i] - mn);
        m_run[mf][i] = mn;
      }
    // P = exp2(s - m), row-sum, LDS roundtrip (C-layout -> A-layout)
    float rs[2][4] = {};
#pragma unroll
    for (int mf = 0; mf < 2; ++mf)
#pragma unroll
      for (int n = 0; n < 4; ++n)
#pragma unroll
        for (int i = 0; i < 4; ++i) {
          float p = exp2f(sf[mf][n][i] - m_run[mf][i]);
          rs[mf][i] += p;
          Ps[w][mf * 16 + q4 * 4 + i][n * 16 + ln] = (_Float16)p;
        }
#pragma unroll
    for (int off = 1; off < 16; off <<= 1)
#pragma unroll
      for (int mf = 0; mf < 2; ++mf)
#pragma unroll
        for (int i = 0; i < 4; ++i) rs[mf][i] += __shfl_xor(rs[mf][i], off);
#pragma unroll
    for (int mf = 0; mf < 2; ++mf)
#pragma unroll
      for (int i = 0; i < 4; ++i)
        l_run[mf][i] = l_run[mf][i] * alpha[mf][i] + rs[mf][i];
#pragma unroll
    for (int mf = 0; mf < 2; ++mf)
#pragma unroll
      for (int n2 = 0; n2 < 4; ++n2)
#pragma unroll
        for (int i = 0; i < 4; ++i) oacc[mf][n2][i] *= alpha[mf][i];
    // O += P V
    halfx8 ap[2][2];
#pragma unroll
    for (int mf = 0; mf < 2; ++mf)
#pragma unroll
      for (int kh = 0; kh < 2; ++kh)
        ap[mf][kh] = *(const halfx8*)&Ps[w][mf * 16 + ln][kh * 32 + q4 * 8];
#pragma unroll
    for (int n2 = 0; n2 < 4; ++n2) {
      halfx8 bv0 = *(const halfx8*)&Vt[n2 * 16 + ln][q4 * 8];
      halfx8 bv1 = *(const halfx8*)&Vt[n2 * 16 + ln][32 + q4 * 8];
#pragma unroll
      for (int mf = 0; mf < 2; ++mf) {
        oacc[mf][n2] = mfma16(ap[mf][0], bv0, oacc[mf][n2]);
        oacc[mf][n2] = mfma16(ap[mf][1], bv1, oacc[mf][n2]);
      }
    }
  }
  // epilogue: row (s, h=q4*4+i), col d
#pragma unroll
  for (int mf = 0; mf < 2; ++mf) {
    int s = sA + mf;
#pragma unroll
    for (int n2 = 0; n2 < 4; ++n2)
#pragma unroll
      for (int i = 0; i < 4; ++i) {
        int h = q4 * 4 + i, d = n2 * 16 + ln;
        aob[(bS + s) * DIM + h * 64 + d] =
            (_Float16)(oacc[mf][n2][i] / l_run[mf][i]);
      }
  }
}

extern "C" void kernel_launch(void* const* d_in, const int* in_sizes, int n_in,
                              void* d_out, int out_size, void* d_ws,
                              size_t ws_size, hipStream_t stream) {
  const float* x    = (const float*)d_in[0];
  const float* wqkv = (const float*)d_in[1];
  const float* bqkv = (const float*)d_in[2];
  const float* wout = (const float*)d_in[3];
  const float* bout = (const float*)d_in[4];
  float* out = (float*)d_out;
  char* ws = (char*)d_ws;
  _Float16* xb    = (_Float16*)(ws);                          // 8 MB
  _Float16* qb    = (_Float16*)(ws + (8u << 20));             // 8 MB
  _Float16* aob   = (_Float16*)(ws + (16u << 20));            // 8 MB
  _Float16* kb    = (_Float16*)(ws + (24u << 20));            // 512 KB
  _Float16* vtb   = (_Float16*)(ws + (24u << 20) + (512u << 10));  // 512 KB
  _Float16* wqb   = (_Float16*)(ws + (25u << 20));            // 2 MB
  _Float16* woutb = (_Float16*)(ws + (27u << 20));            // 2 MB
  _Float16* wredb = (_Float16*)(ws + (29u << 20));            // 256 KB
  float*    bred  = (float*)(ws + (29u << 20) + (256u << 10));

  hipLaunchKernelGGL(prep_convert, dim3(6144), dim3(256), 0, stream,
                     x, wqkv, wout, xb, wqb, woutb);
  hipLaunchKernelGGL(prep_wred, dim3(512), dim3(256), 0, stream,
                     wqkv, bqkv, wredb, bred);
  hipLaunchKernelGGL((gemm_bt<0>), dim3(16, 64), dim3(256), 0, stream,
                     xb, wqb, bqkv, (void*)qb, (void*)nullptr, 1024, 1024);
  hipLaunchKernelGGL((gemm_bt<2>), dim3(2, 64), dim3(256), 0, stream,
                     xb, wredb, bred, (void*)kb, (void*)vtb, 1024, 128);
  hipLaunchKernelGGL(flash_attn2, dim3(512), dim3(256), 0, stream,
                     qb, kb, vtb, aob);
  hipLaunchKernelGGL((gemm_bt<1>), dim3(16, 64), dim3(256), 0, stream,
                     aob, woutb, bout, (void*)out, (void*)nullptr, 1024, 1024);
}

// Round 3
// 197.149 us; speedup vs baseline: 1.5639x; 1.3368x over previous
//
#include <hip/hip_runtime.h>

// Problem: B=2, S=2048, D=1024, H=16, HD=64. fp32 in/out.
// Pipeline exploits head-summed K/V: k_sum = x @ (sum_h Wk_h)^T + sum_h bk_h.
//  1. prep_convert: x, Wq, Wout -> f16
//  2. prep_wred:    head-reduced Wk/Wv (128x1024) + biases
//  3. gemm128<0>:   Q = x @ Wq^T + bq          (4096x1024x1024) -> f16
//  4. gemm_kv:      kv = x @ Wred^T + bred     (4096x128x1024) -> kb + vtb(V^T)
//  5. flash_attn3:  S^T formulation (S^T=K Q^T, O^T=V^T P^T); 16 h x 1 s per wave
//  6. gemm128<1>:   out = ao @ Wout^T + bout   (4096x1024x1024) -> f32

#define S_LEN 2048
#define DIM 1024

using floatx4 = __attribute__((ext_vector_type(4))) float;
using halfx8  = __attribute__((ext_vector_type(8))) _Float16;
using halfx4  = __attribute__((ext_vector_type(4))) _Float16;

__device__ __forceinline__ floatx4 mfma16(halfx8 a, halfx8 b, floatx4 c) {
  return __builtin_amdgcn_mfma_f32_16x16x32_f16(a, b, c, 0, 0, 0);
}

// async global->LDS, 16B per lane; lds dst is wave-uniform base + lane*16
__device__ __forceinline__ void gll16(const void* g, void* l) {
  __builtin_amdgcn_global_load_lds(
      (const __attribute__((address_space(1))) void*)g,
      (__attribute__((address_space(3))) void*)l, 16, 0, 0);
}

// ---------------- prep: fp32 -> f16 conversions ----------------
__global__ __launch_bounds__(256) void prep_convert(
    const float* __restrict__ x, const float* __restrict__ wqkv,
    const float* __restrict__ wout,
    _Float16* __restrict__ xb, _Float16* __restrict__ wqb,
    _Float16* __restrict__ woutb) {
  size_t gid = (size_t)blockIdx.x * 256 + threadIdx.x;
  size_t i4 = gid * 4;
  if (i4 >= 6291456) return;
  const float* src;
  _Float16* dst;
  size_t off;
  if (i4 < 4194304) { src = x; dst = xb; off = i4; }
  else if (i4 < 5242880) { src = wqkv; dst = wqb; off = i4 - 4194304; }
  else { src = wout; dst = woutb; off = i4 - 5242880; }
  float4 v = *(const float4*)(src + off);
  halfx4 o;
  o[0] = (_Float16)v.x; o[1] = (_Float16)v.y;
  o[2] = (_Float16)v.z; o[3] = (_Float16)v.w;
  *(halfx4*)(dst + off) = o;
}

// ---------------- prep: head-reduced K/V weights ----------------
__global__ __launch_bounds__(256) void prep_wred(
    const float* __restrict__ wqkv, const float* __restrict__ bqkv,
    _Float16* __restrict__ wredb, float* __restrict__ bred) {
  int gid = blockIdx.x * 256 + threadIdx.x;  // 131072 threads
  int c = gid >> 10, j = gid & 1023;
  int row0 = (c < 64) ? (1024 + c) : (2048 + c - 64);
  float s = 0.f;
#pragma unroll
  for (int h = 0; h < 16; ++h) s += wqkv[(size_t)(row0 + h * 64) * 1024 + j];
  wredb[gid] = (_Float16)s;
  if (gid < 128) {
    int b0 = (gid < 64) ? (1024 + gid) : (2048 + gid - 64);
    float sb = 0.f;
#pragma unroll
    for (int h = 0; h < 16; ++h) sb += bqkv[b0 + h * 64];
    bred[gid] = sb;
  }
}

// ---------------- GEMM 64Mx128N, BK=64, global_load_lds staging ----------------
// C = A @ W^T + bias. A: M x K f16. W: N x K f16. MODE 0: f16 out; 1: f32 out.
// 256 thr / 4 waves; wave w owns n-cols w*32..w*32+31, all 64 m-rows.
// LDS XOR swizzle: row r's global col-group g (8 halfs) stored at group g^(r&7).
template <int MODE>
__global__ __launch_bounds__(256, 4) void gemm128(
    const _Float16* __restrict__ A, const _Float16* __restrict__ W,
    const float* __restrict__ bias, void* __restrict__ Cv, int K, int ldc) {
  __shared__ _Float16 As[64][64];    // 8 KB
  __shared__ _Float16 Ws[128][64];   // 16 KB
  int tid = threadIdx.x;
  int lane = tid & 63, w = tid >> 6, ln = lane & 15, q4 = lane >> 4;
  int m0 = blockIdx.y * 64, n0 = blockIdx.x * 128;
  int rA = lane >> 3;                        // row-in-chunk 0..7
  int gA = ((lane & 7) ^ rA) * 8;            // swizzled global col-half
  const _Float16* agp = A + (size_t)(m0 + 16 * w + rA) * K + gA;
  const _Float16* wgp = W + (size_t)(n0 + 32 * w + rA) * K + gA;
  floatx4 acc[4][2] = {};
  for (int kt = 0; kt < K; kt += 64) {
    __syncthreads();
#pragma unroll
    for (int j = 0; j < 2; ++j)
      gll16(agp + (size_t)(8 * j) * K + kt, &As[16 * w + 8 * j][0]);
#pragma unroll
    for (int j = 0; j < 4; ++j)
      gll16(wgp + (size_t)(8 * j) * K + kt, &Ws[32 * w + 8 * j][0]);
    __syncthreads();
#pragma unroll
    for (int kh = 0; kh < 2; ++kh) {
      int sw = ((q4 + 4 * kh) ^ (ln & 7)) * 8;
      halfx8 bf[2];
#pragma unroll
      for (int ni = 0; ni < 2; ++ni)
        bf[ni] = *(const halfx8*)&Ws[w * 32 + ni * 16 + ln][sw];
#pragma unroll
      for (int mi = 0; mi < 4; ++mi) {
        halfx8 af = *(const halfx8*)&As[mi * 16 + ln][sw];
#pragma unroll
        for (int ni = 0; ni < 2; ++ni)
          acc[mi][ni] = mfma16(af, bf[ni], acc[mi][ni]);
      }
    }
  }
#pragma unroll
  for (int ni = 0; ni < 2; ++ni) {
    int col = n0 + w * 32 + ni * 16 + ln;
    float bv = bias[col];
#pragma unroll
    for (int mi = 0; mi < 4; ++mi)
#pragma unroll
      for (int i = 0; i < 4; ++i) {
        int row = m0 + mi * 16 + q4 * 4 + i;
        float v = acc[mi][ni][i] + bv;
        if constexpr (MODE == 0)
          ((_Float16*)Cv)[(size_t)row * ldc + col] = (_Float16)v;
        else
          ((float*)Cv)[(size_t)row * ldc + col] = v;
      }
  }
}

// ---------------- KV GEMM (64x64 tile): kb + vtb(V^T) epilogue ----------------
__global__ __launch_bounds__(256) void gemm_kv(
    const _Float16* __restrict__ A, const _Float16* __restrict__ W,
    const float* __restrict__ bias, _Float16* __restrict__ kbo,
    _Float16* __restrict__ vto, int K) {
  __shared__ _Float16 As[64][72];
  __shared__ _Float16 Ws[64][72];
  int tid = threadIdx.x;
  int lane = tid & 63, w = tid >> 6, ln = lane & 15, q4 = lane >> 4;
  int m0 = blockIdx.y * 64, n0 = blockIdx.x * 64;
  int sr = tid >> 2, sc = (tid & 3) * 16;
  const _Float16* ap = A + (size_t)(m0 + sr) * K + sc;
  const _Float16* wp = W + (size_t)(n0 + sr) * K + sc;
  floatx4 acc[4] = {};
  for (int kt = 0; kt < K; kt += 64) {
    __syncthreads();
    *(halfx8*)&As[sr][sc]     = *(const halfx8*)(ap + kt);
    *(halfx8*)&As[sr][sc + 8] = *(const halfx8*)(ap + kt + 8);
    *(halfx8*)&Ws[sr][sc]     = *(const halfx8*)(wp + kt);
    *(halfx8*)&Ws[sr][sc + 8] = *(const halfx8*)(wp + kt + 8);
    __syncthreads();
#pragma unroll
    for (int ks = 0; ks < 2; ++ks) {
      halfx8 af = *(const halfx8*)&As[w * 16 + ln][ks * 32 + q4 * 8];
#pragma unroll
      for (int n = 0; n < 4; ++n) {
        halfx8 bf = *(const halfx8*)&Ws[n * 16 + ln][ks * 32 + q4 * 8];
        acc[n] = mfma16(af, bf, acc[n]);
      }
    }
  }
#pragma unroll
  for (int n = 0; n < 4; ++n) {
    int col = n0 + n * 16 + ln;
    float bv = bias[col];
#pragma unroll
    for (int i = 0; i < 4; ++i) {
      int row = m0 + w * 16 + q4 * 4 + i;
      float v = acc[n][i] + bv;
      if (col < 64) {
        kbo[(size_t)row * 64 + col] = (_Float16)v;
      } else {
        int bb = row >> 11, s = row & 2047;
        vto[(size_t)((bb << 6) + (col - 64)) * S_LEN + s] = (_Float16)v;
      }
    }
  }
}

// ---------------- flash attention v3: transposed-score formulation ----------------
// Per wave: one s, all 16 heads (M=16). S^T = K Q^T (Q is B-operand), so
// C-layout gives h=ln, t=q4*4+reg: mask is ln-uniform, reductions are 2
// shuffle rounds (q4 only), P roundtrip is packed b64/b128, alpha/l scalar.
// O^T = V^T P^T. Block = 4 waves = 4 consecutive s. Grid 1024, LPT order.
__global__ __launch_bounds__(256, 4) void flash_attn3(
    const _Float16* __restrict__ Qb, const _Float16* __restrict__ kb,
    const _Float16* __restrict__ vtb, _Float16* __restrict__ aob) {
  __shared__ _Float16 Ks[64][72];     // K tile [t][d]
  __shared__ _Float16 Vt[64][72];     // V^T tile [d][t]
  __shared__ _Float16 Ps[4][16][80];  // per-wave P[h][t], pitch 160 B
  int tid = threadIdx.x;
  int lane = tid & 63, w = tid >> 6, ln = lane & 15, q4 = lane >> 4;
  int idx = 1023 - (int)blockIdx.x;   // longest chunks first
  int c = idx >> 1, b = idx & 1;
  int s0 = c * 4;
  int s = s0 + w;
  size_t bS = (size_t)b * S_LEN;
  const _Float16* kbase = kb + bS * 64;
  const _Float16* vbase = vtb + (size_t)b * 64 * S_LEN;

  // Q as B-operand: B[k=d][n=h] -> lane(ln,q4): Q[h=ln][d=kh*32+q4*8+j]
  halfx8 bq0 = *(const halfx8*)(Qb + (bS + s) * DIM + ln * 64 + q4 * 8);
  halfx8 bq1 = *(const halfx8*)(Qb + (bS + s) * DIM + ln * 64 + 32 + q4 * 8);

  float m_run = -1e30f, l_run = 0.f;
  floatx4 oacc[4] = {};
  const float sc_log2 = 0.18033688011112042f;  // (1/sqrt(64)) * log2(e)
  int st = tid >> 2, scc = (tid & 3) * 16;
  int nt = (s0 >> 6) + 1;
  _Float16* Pw = &Ps[w][0][0];

  for (int it = 0; it < nt; ++it) {
    int t0 = it << 6;
    __syncthreads();
    *(halfx8*)&Ks[st][scc]     = *(const halfx8*)(kbase + (size_t)(t0 + st) * 64 + scc);
    *(halfx8*)&Ks[st][scc + 8] = *(const halfx8*)(kbase + (size_t)(t0 + st) * 64 + scc + 8);
    *(halfx8*)&Vt[st][scc]     = *(const halfx8*)(vbase + (size_t)st * S_LEN + t0 + scc);
    *(halfx8*)&Vt[st][scc + 8] = *(const halfx8*)(vbase + (size_t)st * S_LEN + t0 + scc + 8);
    __syncthreads();

    // S^T = K Q^T: frag tf rows t=tf*16+ln (A-operand), cols h (B=Q)
    floatx4 sf[4];
#pragma unroll
    for (int tf = 0; tf < 4; ++tf) {
      halfx8 ak0 = *(const halfx8*)&Ks[tf * 16 + ln][q4 * 8];
      halfx8 ak1 = *(const halfx8*)&Ks[tf * 16 + ln][32 + q4 * 8];
      floatx4 z = {};
      z = mfma16(ak0, bq0, z);
      sf[tf] = mfma16(ak1, bq1, z);
    }
    // scale (+ causal mask only on the final tile; earlier tiles all t <= s)
    if (it == nt - 1) {
#pragma unroll
      for (int tf = 0; tf < 4; ++tf)
#pragma unroll
        for (int i = 0; i < 4; ++i) {
          int t = t0 + tf * 16 + q4 * 4 + i;
          sf[tf][i] = (t > s) ? -1e30f : sf[tf][i] * sc_log2;
        }
    } else {
#pragma unroll
      for (int tf = 0; tf < 4; ++tf)
#pragma unroll
        for (int i = 0; i < 4; ++i) sf[tf][i] *= sc_log2;
    }
    // max over t: in-lane 16 values, then across q4 (2 rounds)
    float tm = fmaxf(fmaxf(sf[0][0], sf[0][1]), fmaxf(sf[0][2], sf[0][3]));
#pragma unroll
    for (int tf = 1; tf < 4; ++tf)
      tm = fmaxf(tm, fmaxf(fmaxf(sf[tf][0], sf[tf][1]),
                           fmaxf(sf[tf][2], sf[tf][3])));
    tm = fmaxf(tm, __shfl_xor(tm, 16));
    tm = fmaxf(tm, __shfl_xor(tm, 32));
    float mn = fmaxf(m_run, tm);
    float alpha = exp2f(m_run - mn);
    m_run = mn;
    // P = exp2(s - m); packed f16; row-sum
    float rs = 0.f;
    halfx4 pk[4];
#pragma unroll
    for (int tf = 0; tf < 4; ++tf)
#pragma unroll
      for (int i = 0; i < 4; ++i) {
        float p = exp2f(sf[tf][i] - mn);
        rs += p;
        pk[tf][i] = (_Float16)p;
      }
    rs += __shfl_xor(rs, 16);
    rs += __shfl_xor(rs, 32);
    l_run = l_run * alpha + rs;
#pragma unroll
    for (int n2 = 0; n2 < 4; ++n2)
#pragma unroll
      for (int i = 0; i < 4; ++i) oacc[n2][i] *= alpha;
    // P roundtrip: write P[h=ln][t=tf*16+q4*4..+3] (b64), read B-frags (b128)
#pragma unroll
    for (int tf = 0; tf < 4; ++tf)
      *(halfx4*)&Pw[ln * 80 + tf * 16 + q4 * 4] = pk[tf];
    halfx8 bp0 = *(const halfx8*)&Pw[ln * 80 + q4 * 8];
    halfx8 bp1 = *(const halfx8*)&Pw[ln * 80 + 32 + q4 * 8];
    // O^T += V^T P^T: frag n2 rows d=n2*16+ln (A-operand)
#pragma unroll
    for (int n2 = 0; n2 < 4; ++n2) {
      halfx8 av0 = *(const halfx8*)&Vt[n2 * 16 + ln][q4 * 8];
      halfx8 av1 = *(const halfx8*)&Vt[n2 * 16 + ln][32 + q4 * 8];
      oacc[n2] = mfma16(av0, bp0, oacc[n2]);
      oacc[n2] = mfma16(av1, bp1, oacc[n2]);
    }
  }
  // epilogue: O^T frag n2: h=ln, d=n2*16+q4*4+i (i contiguous -> halfx4)
  float inv = 1.0f / l_run;
#pragma unroll
  for (int n2 = 0; n2 < 4; ++n2) {
    halfx4 o;
#pragma unroll
    for (int i = 0; i < 4; ++i) o[i] = (_Float16)(oacc[n2][i] * inv);
    *(halfx4*)(aob + (bS + s) * DIM + ln * 64 + n2 * 16 + q4 * 4) = o;
  }
}

extern "C" void kernel_launch(void* const* d_in, const int* in_sizes, int n_in,
                              void* d_out, int out_size, void* d_ws,
                              size_t ws_size, hipStream_t stream) {
  const float* x    = (const float*)d_in[0];
  const float* wqkv = (const float*)d_in[1];
  const float* bqkv = (const float*)d_in[2];
  const float* wout = (const float*)d_in[3];
  const float* bout = (const float*)d_in[4];
  float* out = (float*)d_out;
  char* ws = (char*)d_ws;
  _Float16* xb    = (_Float16*)(ws);                               // 8 MB
  _Float16* qb    = (_Float16*)(ws + (8u << 20));                  // 8 MB
  _Float16* aob   = (_Float16*)(ws + (16u << 20));                 // 8 MB
  _Float16* kb    = (_Float16*)(ws + (24u << 20));                 // 512 KB
  _Float16* vtb   = (_Float16*)(ws + (24u << 20) + (512u << 10));  // 512 KB
  _Float16* wqb   = (_Float16*)(ws + (25u << 20));                 // 2 MB
  _Float16* woutb = (_Float16*)(ws + (27u << 20));                 // 2 MB
  _Float16* wredb = (_Float16*)(ws + (29u << 20));                 // 256 KB
  float*    bred  = (float*)(ws + (29u << 20) + (256u << 10));

  hipLaunchKernelGGL(prep_convert, dim3(6144), dim3(256), 0, stream,
                     x, wqkv, wout, xb, wqb, woutb);
  hipLaunchKernelGGL(prep_wred, dim3(512), dim3(256), 0, stream,
                     wqkv, bqkv, wredb, bred);
  hipLaunchKernelGGL((gemm128<0>), dim3(8, 64), dim3(256), 0, stream,
                     xb, wqb, bqkv, (void*)qb, 1024, 1024);
  hipLaunchKernelGGL(gemm_kv, dim3(2, 64), dim3(256), 0, stream,
                     xb, wredb, bred, kb, vtb, 1024);
  hipLaunchKernelGGL(flash_attn3, dim3(1024), dim3(256), 0, stream,
                     qb, kb, vtb, aob);
  hipLaunchKernelGGL((gemm128<1>), dim3(8, 64), dim3(256), 0, stream,
                     aob, woutb, bout, (void*)out, 1024, 1024);
}